// Round 23
// baseline (150.581 us; speedup 1.0000x reference)
//
#include <hip/hip_runtime.h>
#include <stdint.h>

// Problem constants
#define B_   2
#define T_   4096
#define C_   768
#define H_   12
#define D_   64
#define BH_  24      // B_*H_
#define M_   8192    // B_*T_
#define K_   768
#define N1_  2304    // 3*C_

#define NEG_BIG (-1.0e30f)
// Q pre-scale: (1/sqrt(D)) * log2(e) -> attention runs in exp2 domain
#define QSCALE 0.18033688011112042f

typedef short bf16x8 __attribute__((ext_vector_type(8)));
typedef float f32x4  __attribute__((ext_vector_type(4)));
typedef float f32x16 __attribute__((ext_vector_type(16)));
typedef uint32_t u32x4 __attribute__((ext_vector_type(4)));
typedef int i32x2 __attribute__((ext_vector_type(2)));

typedef const __attribute__((address_space(1))) void* as1cv;
typedef __attribute__((address_space(3))) void*       as3v;

__device__ __forceinline__ void gload_lds16(const void* g, void* l) {
  __builtin_amdgcn_global_load_lds((as1cv)g, (as3v)l, 16, 0, 0);
}

// fp32 -> bf16 bits, round-to-nearest-even (input-fidelity paths).
// NOTE: v_cvt_pk_bf16_f32 inline-asm is POISONED on this toolchain (R2: NaN,
// R6: absmax 7.4e30). Software paths only.
// NOTE2 (R19): fixed-shift softmax (max-free) causes scratch spill at 128
// VGPR — keep defer-max; it also fences the scheduler's overlap window.
// NOTE3 (R20): s_setprio around attn MFMAs = -5% (no wave role-split here).
__device__ __forceinline__ unsigned short f2bf(float f) {
  uint32_t x = __builtin_bit_cast(uint32_t, f);
  uint32_t r = (x + 0x7fffu + ((x >> 16) & 1u)) >> 16;
  return (unsigned short)r;
}

// cheap scalar pack: round-half-up, 2 VALU ops (<=0.5 ulp; 4x absmax headroom)
__device__ __forceinline__ unsigned short f2bf_hu(float f) {
  return (unsigned short)((__builtin_bit_cast(uint32_t, f) + 0x8000u) >> 16);
}

// cheap pair pack: round-half-up + byte-select (3 VALU via v_perm_b32)
#if __has_builtin(__builtin_amdgcn_perm)
__device__ __forceinline__ uint32_t pack_hu(float lo, float hi) {
  uint32_t a = __builtin_bit_cast(uint32_t, lo) + 0x8000u;
  uint32_t b = __builtin_bit_cast(uint32_t, hi) + 0x8000u;
  return __builtin_amdgcn_perm(b, a, 0x07060302u);
}
#else
__device__ __forceinline__ uint32_t pack_hu(float lo, float hi) {
  uint32_t a = __builtin_bit_cast(uint32_t, lo) + 0x8000u;
  uint32_t b = __builtin_bit_cast(uint32_t, hi) + 0x8000u;
  return (b & 0xFFFF0000u) | (a >> 16);
}
#endif

// unpack one bf16 half of a packed pair to f32 (1-2 VALU)
__device__ __forceinline__ float bfu(uint32_t w, int hb) {
  return __builtin_bit_cast(float, hb ? (w & 0xFFFF0000u) : (w << 16));
}

// 3-input max -> v_max3_f32 (clang fuses nested fmaxf)
__device__ __forceinline__ float max3f(float a, float b, float c) {
  return fmaxf(fmaxf(a, b), c);
}

#if __has_builtin(__builtin_amdgcn_permlane32_swap)
#define HAVE_PLSWAP 1
#else
#define HAVE_PLSWAP 0
#endif

// native 2^x (v_exp_f32)
#if __has_builtin(__builtin_amdgcn_exp2f)
__device__ __forceinline__ float fast_exp2(float x) { return __builtin_amdgcn_exp2f(x); }
#else
__device__ __forceinline__ float fast_exp2(float x) { return __expf(x * 0.69314718056f); }
#endif

// ------------------- fused prep: weight transposes + x cast, ONE launch
// blocks [0, 2304): transpose+cast  a[768][2304]->oa[2304][768],
//                   b[768][768]->ob[768][768]   (32x32 tiles, 256 thr)
// blocks [2304, 3328): grid-stride cast x fp32 -> bf16 (float4 granules)
__global__ void prep_kernel(const float* __restrict__ x, unsigned short* __restrict__ xb,
                            const float* __restrict__ a, unsigned short* __restrict__ oa,
                            const float* __restrict__ b, unsigned short* __restrict__ ob) {
  __shared__ float tile[32][33];
  const int bid = blockIdx.x;
  if (bid < 2304) {
    const int bx = bid % 96, by = bid / 96;
    const float* in; unsigned short* out; int N, cb;
    if (bx < 72) { in = a; out = oa; N = 2304; cb = bx; }
    else         { in = b; out = ob; N = 768;  cb = bx - 72; }
    const int tx = threadIdx.x & 31, ty = threadIdx.x >> 5;  // 32 x 8
    const int n = cb * 32 + tx;
    #pragma unroll
    for (int r = 0; r < 4; ++r) {
      int k = by * 32 + ty + r * 8;
      tile[ty + r * 8][tx] = in[(size_t)k * N + n];
    }
    __syncthreads();
    const int k = by * 32 + tx;
    #pragma unroll
    for (int r = 0; r < 4; ++r) {
      int nn = cb * 32 + ty + r * 8;
      out[(size_t)nn * K_ + k] = f2bf(tile[tx][ty + r * 8]);
    }
  } else {
    const int n4 = M_ * K_ / 4;
    const int idx = (bid - 2304) * 256 + threadIdx.x;
    const int stride = 1024 * 256;
    for (int i = idx; i < n4; i += stride) {
      float4 v = reinterpret_cast<const float4*>(x)[i];
      ushort4 o;
      o.x = f2bf(v.x); o.y = f2bf(v.y); o.z = f2bf(v.z); o.w = f2bf(v.w);
      reinterpret_cast<ushort4*>(xb)[i] = o;
    }
  }
}

// ---------------------------------------------------------------- GEMM
// C[M][N] = A[M][768] * BT[N][768]^T + bias.  BK=64, 32 MFMAs per barrier.
// R23: XCD-aware A-panel clustering — all blocks sharing an A-panel (same
// m0) land on ONE XCD, consecutive slots process the same panel: A is read
// once per XCD (L2-served re-reads instead of ~8x via L3). Bijective for
// nwg%8==0 (gy=18 and gy=6). B (3.4MB) stays L2-resident per XCD.
// MODE-0 epilogue via LDS bounce (R18): deposit bf16 at tiled-layout
// positions in LDS, flush as 2048 coalesced 16B stores.
// MODE 1: plain fp32 store to fo[M][768] (already 64B-coalesced).
template <int MODE>
__global__ __launch_bounds__(256) void gemm_kernel(
    const unsigned short* __restrict__ A, const unsigned short* __restrict__ BT,
    const float* __restrict__ bias,
    unsigned short* __restrict__ o0, unsigned short* __restrict__ o1,
    unsigned short* __restrict__ o2, float* __restrict__ fo) {
  // A panels: [0, 8192) ushorts (two k-sub panels), B panels: [8192, 16384)
  __shared__ __align__(16) unsigned short SB[16384];
  const int tid = threadIdx.x;
  const int w = tid >> 6, lane = tid & 63;
  const int g = lane >> 4, c16 = lane & 15;
  const int wr = w >> 1, wc = w & 1;

  // XCD-aware remap (bid%8 ~ XCD): m_idx = (s/gy)*8 + xcd, n_idx = s%gy
  const int gy = gridDim.y;
  const int bid = blockIdx.y * gridDim.x + blockIdx.x;
  const int xcd = bid & 7, s0 = bid >> 3;
  const int m0 = ((s0 / gy) * 8 + xcd) * 128;
  const int n0 = (s0 % gy) * 128;

  f32x4 acc[4][4] = {};

  for (int k0 = 0; k0 < K_; k0 += 64) {
    __syncthreads();
    #pragma unroll
    for (int s = 0; s < 2; ++s)
      #pragma unroll
      for (int q = 0; q < 2; ++q) {
        const int ch = (w * 2 + q) * 64 + lane;     // 0..511
        const int row = ch >> 2, kb = ch & 3;       // 128 rows x 4 x 16B
        gload_lds16(A  + (size_t)(m0 + row) * K_ + k0 + s * 32 + kb * 8,
                    &SB[s * 4096 + (w * 2 + q) * 512]);
        gload_lds16(BT + (size_t)(n0 + row) * K_ + k0 + s * 32 + kb * 8,
                    &SB[8192 + s * 4096 + (w * 2 + q) * 512]);
      }
    __syncthreads();
    #pragma unroll
    for (int s = 0; s < 2; ++s) {
      bf16x8 af[4], bfr[4];
      #pragma unroll
      for (int i = 0; i < 4; ++i) {
        af[i]  = *reinterpret_cast<const bf16x8*>(&SB[s * 4096 + (wr * 64 + i * 16 + c16) * 32 + g * 8]);
        bfr[i] = *reinterpret_cast<const bf16x8*>(&SB[8192 + s * 4096 + (wc * 64 + i * 16 + c16) * 32 + g * 8]);
      }
      #pragma unroll
      for (int i = 0; i < 4; ++i)
        #pragma unroll
        for (int j = 0; j < 4; ++j)
          acc[i][j] = __builtin_amdgcn_mfma_f32_16x16x32_bf16(af[i], bfr[j], acc[i][j], 0, 0, 0);
    }
  }

  if constexpr (MODE == 0) {
    const int which = n0 / 768;
    __syncthreads();  // staging reads complete; SB now epilogue buffer
    #pragma unroll
    for (int i = 0; i < 4; ++i) {
      const int ttl0 = wr * 64 + i * 16 + g * 4;   // local token row (j adds 0..3)
      #pragma unroll
      for (int j2 = 0; j2 < 4; ++j2) {
        const int nn = wc * 64 + j2 * 16 + c16;    // 0..127
        const float bv = bias[n0 + nn];
        const int dd = nn & 63;
        unsigned short* Lh = &SB[(nn >> 6) * 8192];
        if (which == 0) {
          const int base = ttl0 * 64 + dd;         // [ttl][dd], stride 64 per j
          #pragma unroll
          for (int j = 0; j < 4; ++j)
            Lh[base + j * 64] = f2bf_hu((acc[i][j2][j] + bv) * QSCALE);
        } else if (which == 1) {
          // K tiled: stride 8 per j (ttl&31 never crosses 32 within j-run)
          const int base = ((ttl0 >> 5) * 4 + (dd >> 4)) * 512 +
                           ((ttl0 & 31) + ((dd >> 3) & 1) * 32) * 8 + (dd & 7);
          #pragma unroll
          for (int j = 0; j < 4; ++j)
            Lh[base + j * 8] = f2bf_hu(acc[i][j2][j] + bv);
        } else {
          // V^T tiled: stride 1 per j (ttl&7 in {0,4}, no 8-crossing) -> 8B write
          const int base = (ttl0 >> 6) * 4096 + (dd >> 5) * 2048 +
                           ((ttl0 >> 4) & 3) * 512 +
                           ((dd & 31) + ((ttl0 >> 3) & 1) * 32) * 8 + (ttl0 & 7);
          uint2 pr = {pack_hu(acc[i][j2][0] + bv, acc[i][j2][1] + bv),
                      pack_hu(acc[i][j2][2] + bv, acc[i][j2][3] + bv)};
          *reinterpret_cast<uint2*>(&Lh[base]) = pr;
        }
      }
    }
    __syncthreads();
    // coalesced flush: 8 x 16B per thread
    const int tt0 = m0 & 4095, bb2 = m0 >> 12;
    const int hhA = (n0 - which * 768) >> 6;
    unsigned short* outp = (which == 0) ? o0 : (which == 1) ? o1 : o2;
    size_t gbase[2];
    #pragma unroll
    for (int h2 = 0; h2 < 2; ++h2) {
      const size_t hb = ((size_t)bb2 * H_ + hhA + h2) * T_ * D_;
      gbase[h2] = hb + (which == 0 ? (size_t)tt0 * 64
                       : which == 1 ? (size_t)(tt0 >> 5) * 2048
                                    : (size_t)(tt0 >> 6) * 4096);
    }
    #pragma unroll
    for (int c = 0; c < 8; ++c) {
      const int idx = (c * 256 + tid) * 8;     // ushort index, 16B-aligned
      const int h2 = idx >> 13, off = idx & 8191;
      u32x4 val = *reinterpret_cast<const u32x4*>(&SB[idx]);
      *reinterpret_cast<u32x4*>(&outp[gbase[h2] + off]) = val;
    }
  } else {
    #pragma unroll
    for (int i = 0; i < 4; ++i) {
      const int mbase = m0 + wr * 64 + i * 16 + g * 4;
      #pragma unroll
      for (int j2 = 0; j2 < 4; ++j2) {
        const int n = n0 + wc * 64 + j2 * 16 + c16;
        const float bv = bias[n];
        #pragma unroll
        for (int j = 0; j < 4; ++j)
          fo[(size_t)(mbase + j) * 768 + n] = acc[i][j2][j] + bv;
      }
    }
  }
}

// ---------------------------------------------------------------- flash attention
// R18 defer-max form (best measured: 79.7 us attn).
// 1 strip/block longest-first; 4 waves; 64 q-rows/wave (S-tiles A,B);
// kv round-robin (it ≡ wv mod 4); K-prefetch rotation; v_max3 reduce;
// exp2 domain; defer-max (also fences scheduler overlap — R19 spill lesson).
// No setprio (R20: -5%, no wave role-split here).
__global__ __launch_bounds__(256, 2) void attn_kernel(
    const unsigned short* __restrict__ Qb, const unsigned short* __restrict__ Kb,
    const unsigned short* __restrict__ Vt, unsigned short* __restrict__ Yb) {
  __shared__ float Ml[3][2][64];
  __shared__ float Ll[3][2][64];
  __shared__ uint32_t Ylp[3][32][64];  // [partial][reg-pair][lane], bf16x2

  const int tidx = threadIdx.x;
  const int wv = tidx >> 6;       // 0..3: kv-split partner index
  const int lane = tidx & 63;
  const int q31 = lane & 31, hi = lane >> 5;
  const int bid = blockIdx.x;
  const int bh = bid % BH_;                     // bid%8 == bh%8 -> bh->XCD locality
  const int strip = (T_ / 64 - 1) - bid / BH_;  // 63..0, longest first
  const int q0 = strip * 64;
  const int qgA = q0 + q31;        // lane's q row, S-tile A
  const int qgB = q0 + 32 + q31;   // lane's q row, S-tile B

  const int bb = bh / H_, hh = bh % H_;
  const size_t hoff = (size_t)bh * T_ * D_;
  const unsigned short* Qh = Qb + hoff;
  const unsigned short* Kh = Kb + hoff + lane * 8;  // tiled: all frag loads + lane*8
  const unsigned short* Vh = Vt + hoff + lane * 8;

  // Q fragments for both S-tiles: B-operand, col = q31, k = s*16 + hi*8 + e
  bf16x8 qfA[4], qfB[4];
  #pragma unroll
  for (int s = 0; s < 4; ++s) {
    qfA[s] = *reinterpret_cast<const bf16x8*>(&Qh[(size_t)qgA * D_ + s * 16 + hi * 8]);
    qfB[s] = *reinterpret_cast<const bf16x8*>(&Qh[(size_t)qgB * D_ + s * 16 + hi * 8]);
  }

  float mA = NEG_BIG, lA = 0.f, mB = NEG_BIG, lB = 0.f;
  f32x16 yA0 = {}, yA1 = {}, yB0 = {}, yB1 = {};

  const int nt = strip + 1;  // kv tiles 0..strip

  // prologue: K fragments for my first tile
  bf16x8 kf[8];
  {
    const unsigned short* kT = Kh + wv * 4096;
    #pragma unroll
    for (int s = 0; s < 8; ++s)
      kf[s] = *reinterpret_cast<const bf16x8*>(kT + (s >> 2) * 2048 + (s & 3) * 512);
  }

  for (int it = wv; it < nt; it += 4) {
    const int kv0 = it << 6;

    // ---- V fragments (consumed after softmax; latency hidden under QK)
    const unsigned short* vT = Vh + it * 4096;
    bf16x8 vlo[4], vhi[4];
    #pragma unroll
    for (int ks = 0; ks < 4; ++ks) {
      vlo[ks] = *reinterpret_cast<const bf16x8*>(vT + ks * 512);
      vhi[ks] = *reinterpret_cast<const bf16x8*>(vT + 2048 + ks * 512);
    }

    // ---- S^T = K * Q^T for both S-tiles (kf resident from prefetch)
    f32x16 sA0 = {}, sA1 = {}, sB0 = {}, sB1 = {};
    #pragma unroll
    for (int s = 0; s < 4; ++s) {
      sA0 = __builtin_amdgcn_mfma_f32_32x32x16_bf16(kf[s], qfA[s], sA0, 0, 0, 0);
      sB0 = __builtin_amdgcn_mfma_f32_32x32x16_bf16(kf[s], qfB[s], sB0, 0, 0, 0);
    }
    #pragma unroll
    for (int s = 0; s < 4; ++s) {
      sA1 = __builtin_amdgcn_mfma_f32_32x32x16_bf16(kf[4 + s], qfA[s], sA1, 0, 0, 0);
      sB1 = __builtin_amdgcn_mfma_f32_32x32x16_bf16(kf[4 + s], qfB[s], sB1, 0, 0, 0);
    }

    // ---- K prefetch for MY next tile (in-place rotate after last kf use)
    {
      const unsigned short* kT = Kh + (it + 4) * 4096;
      #pragma unroll
      for (int s = 0; s < 8; ++s)
        kf[s] = *reinterpret_cast<const bf16x8*>(kT + (s >> 2) * 2048 + (s & 3) * 512);
    }

    // ---- causal mask: only the diagonal tile (it == strip, wave-uniform).
    if (it == strip) {
      #pragma unroll
      for (int r = 0; r < 16; ++r) {
        const int kvl = (r & 3) + 8 * (r >> 2) + 4 * hi;
        sA0[r] = (kv0 + kvl > qgA)      ? NEG_BIG : sA0[r];
        sA1[r] = NEG_BIG;
        sB1[r] = (kv0 + 32 + kvl > qgB) ? NEG_BIG : sB1[r];
      }
    }

// ---- column max via v_max3 triples (exact): 32 values -> tmax
#define COLMAX(S0, S1, TM)                                                    \
    {                                                                         \
      float g0 = max3f(S0[0], S0[1], S0[2]);                                  \
      float g1 = max3f(S0[3], S0[4], S0[5]);                                  \
      float g2 = max3f(S0[6], S0[7], S0[8]);                                  \
      float g3 = max3f(S0[9], S0[10], S0[11]);                                \
      float g4 = max3f(S0[12], S0[13], S0[14]);                               \
      float g5 = max3f(S0[15], S1[0], S1[1]);                                 \
      float g6 = max3f(S1[2], S1[3], S1[4]);                                  \
      float g7 = max3f(S1[5], S1[6], S1[7]);                                  \
      float g8 = max3f(S1[8], S1[9], S1[10]);                                 \
      float g9 = max3f(S1[11], S1[12], S1[13]);                               \
      float ga = fmaxf(S1[14], S1[15]);                                       \
      float h0 = max3f(g0, g1, g2);                                           \
      float h1 = max3f(g3, g4, g5);                                           \
      float h2 = max3f(g6, g7, g8);                                           \
      float h3 = max3f(g9, ga, h0);                                           \
      TM = max3f(h1, h2, h3);                                                 \
      TM = fmaxf(TM, __shfl_xor(TM, 32));                                     \
    }

    // ======== softmax + PV, S-tile A ========
    {
      float tmax;
      COLMAX(sA0, sA1, tmax)

      if (__any(tmax > mA + 11.5f)) {
        const float mnew = fmaxf(mA, tmax);
        const float alpha = fast_exp2(mA - mnew);
        mA = mnew;
        lA *= alpha;
        #pragma unroll
        for (int r = 0; r < 16; ++r) { yA0[r] *= alpha; yA1[r] *= alpha; }
      }
      #pragma unroll
      for (int r = 0; r < 16; ++r) {
        sA0[r] = fast_exp2(sA0[r] - mA);
        sA1[r] = fast_exp2(sA1[r] - mA);
      }
      float a[16];
      #pragma unroll
      for (int r = 0; r < 8; ++r) a[r] = sA0[2 * r] + sA0[2 * r + 1];
      #pragma unroll
      for (int r = 0; r < 8; ++r) a[8 + r] = sA1[2 * r] + sA1[2 * r + 1];
      #pragma unroll
      for (int st = 8; st > 0; st >>= 1)
        #pragma unroll
        for (int r = 0; r < 16; ++r) if (r < st) a[r] = a[r] + a[r + st];
      float rsum = a[0];
      rsum += __shfl_xor(rsum, 32);
      lA += rsum;

      bf16x8 pf[4];
#if HAVE_PLSWAP
#define MK_PF(KS, SH, GA, HA)                                                 \
      {                                                                       \
        uint32_t g0 = pack_hu(SH[(GA)*4 + 0], SH[(GA)*4 + 1]);                \
        uint32_t g1 = pack_hu(SH[(GA)*4 + 2], SH[(GA)*4 + 3]);                \
        uint32_t h0 = pack_hu(SH[(HA)*4 + 0], SH[(HA)*4 + 1]);                \
        uint32_t h1 = pack_hu(SH[(HA)*4 + 2], SH[(HA)*4 + 3]);                \
        i32x2 r0 = __builtin_amdgcn_permlane32_swap((int)g0, (int)h0, false, false); \
        i32x2 r1 = __builtin_amdgcn_permlane32_swap((int)g1, (int)h1, false, false); \
        u32x4 t;                                                              \
        t[0] = (uint32_t)r0[0];                                               \
        t[1] = (uint32_t)r1[0];                                               \
        t[2] = (uint32_t)r0[1];                                               \
        t[3] = (uint32_t)r1[1];                                               \
        pf[KS] = __builtin_bit_cast(bf16x8, t);                               \
      }
#else
#define MK_PF(KS, SH, GA, HA)                                                 \
      {                                                                       \
        uint32_t g0 = pack_hu(SH[(GA)*4 + 0], SH[(GA)*4 + 1]);                \
        uint32_t g1 = pack_hu(SH[(GA)*4 + 2], SH[(GA)*4 + 3]);                \
        uint32_t h0 = pack_hu(SH[(HA)*4 + 0], SH[(HA)*4 + 1]);                \
        uint32_t h1 = pack_hu(SH[(HA)*4 + 2], SH[(HA)*4 + 3]);                \
        uint32_t sg0 = (uint32_t)__shfl_xor((int)g0, 32);                     \
        uint32_t sg1 = (uint32_t)__shfl_xor((int)g1, 32);                     \
        uint32_t sh0 = (uint32_t)__shfl_xor((int)h0, 32);                     \
        uint32_t sh1 = (uint32_t)__shfl_xor((int)h1, 32);                     \
        u32x4 t;                                                              \
        t[0] = hi ? sh0 : g0;                                                 \
        t[1] = hi ? sh1 : g1;                                                 \
        t[2] = hi ? h0 : sg0;                                                 \
        t[3] = hi ? h1 : sg1;                                                 \
        pf[KS] = __builtin_bit_cast(bf16x8, t);                               \
      }
#endif
      MK_PF(0, sA0, 0, 1)
      MK_PF(1, sA0, 2, 3)
      MK_PF(2, sA1, 0, 1)
      MK_PF(3, sA1, 2, 3)

      #pragma unroll
      for (int ks = 0; ks < 4; ++ks)
        yA0 = __builtin_amdgcn_mfma_f32_32x32x16_bf16(vlo[ks], pf[ks], yA0, 0, 0, 0);
      #pragma unroll
      for (int ks = 0; ks < 4; ++ks)
        yA1 = __builtin_amdgcn_mfma_f32_32x32x16_bf16(vhi[ks], pf[ks], yA1, 0, 0, 0);
    }

    // ======== softmax + PV, S-tile B ========
    {
      float tmax;
      COLMAX(sB0, sB1, tmax)

      if (__any(tmax > mB + 11.5f)) {
        const float mnew = fmaxf(mB, tmax);
        const float alpha = fast_exp2(mB - mnew);
        mB = mnew;
        lB *= alpha;
        #pragma unroll
        for (int r = 0; r < 16; ++r) { yB0[r] *= alpha; yB1[r] *= alpha; }
      }
      #pragma unroll
      for (int r = 0; r < 16; ++r) {
        sB0[r] = fast_exp2(sB0[r] - mB);
        sB1[r] = fast_exp2(sB1[r] - mB);
      }
      float a[16];
      #pragma unroll
      for (int r = 0; r < 8; ++r) a[r] = sB0[2 * r] + sB0[2 * r + 1];
      #pragma unroll
      for (int r = 0; r < 8; ++r) a[8 + r] = sB1[2 * r] + sB1[2 * r + 1];
      #pragma unroll
      for (int st = 8; st > 0; st >>= 1)
        #pragma unroll
        for (int r = 0; r < 16; ++r) if (r < st) a[r] = a[r] + a[r + st];
      float rsum = a[0];
      rsum += __shfl_xor(rsum, 32);
      lB += rsum;

      bf16x8 pf[4];
      MK_PF(0, sB0, 0, 1)
      MK_PF(1, sB0, 2, 3)
      MK_PF(2, sB1, 0, 1)
      MK_PF(3, sB1, 2, 3)
#undef MK_PF
#undef COLMAX

      #pragma unroll
      for (int ks = 0; ks < 4; ++ks)
        yB0 = __builtin_amdgcn_mfma_f32_32x32x16_bf16(vlo[ks], pf[ks], yB0, 0, 0, 0);
      #pragma unroll
      for (int ks = 0; ks < 4; ++ks)
        yB1 = __builtin_amdgcn_mfma_f32_32x32x16_bf16(vhi[ks], pf[ks], yB1, 0, 0, 0);
    }
  }

  // ---- cross-wave merge: waves 1-3 publish (bf16 pairs), wave0 combines
  if (wv > 0) {
    Ml[wv - 1][0][lane] = mA; Ml[wv - 1][1][lane] = mB;
    Ll[wv - 1][0][lane] = lA; Ll[wv - 1][1][lane] = lB;
    #pragma unroll
    for (int r = 0; r < 8; ++r) {
      Ylp[wv - 1][r][lane]      = pack_hu(yA0[2 * r], yA0[2 * r + 1]);
      Ylp[wv - 1][8 + r][lane]  = pack_hu(yA1[2 * r], yA1[2 * r + 1]);
      Ylp[wv - 1][16 + r][lane] = pack_hu(yB0[2 * r], yB0[2 * r + 1]);
      Ylp[wv - 1][24 + r][lane] = pack_hu(yB1[2 * r], yB1[2 * r + 1]);
    }
  }
  __syncthreads();
  if (wv == 0) {
    // ---- S-tile A
    {
      float mm = mA;
      #pragma unroll
      for (int p = 0; p < 3; ++p) mm = fmaxf(mm, Ml[p][0][lane]);
      const float aw = fast_exp2(mA - mm);
      float ap[3];
      float ll = lA * aw;
      #pragma unroll
      for (int p = 0; p < 3; ++p) {
        ap[p] = fast_exp2(Ml[p][0][lane] - mm);   // 0 for empty partials
        ll += Ll[p][0][lane] * ap[p];
      }
      const float inv = 1.f / ll;
      const size_t ro = ((size_t)bb * T_ + qgA) * C_ + hh * D_;
      #pragma unroll
      for (int q2 = 0; q2 < 4; ++q2) {
        float v[8];
        #pragma unroll
        for (int e = 0; e < 4; ++e) {
          const int pr = q2 * 2 + (e >> 1), hb2 = e & 1;
          float t0 = yA0[q2 * 4 + e] * aw;
          float t1 = yA1[q2 * 4 + e] * aw;
          #pragma unroll
          for (int p = 0; p < 3; ++p) {
            t0 += bfu(Ylp[p][pr][lane], hb2) * ap[p];
            t1 += bfu(Ylp[p][8 + pr][lane], hb2) * ap[p];
          }
          v[e] = t0 * inv;
          v[4 + e] = t1 * inv;
        }
        uint2 pr0 = {pack_hu(v[0], v[1]), pack_hu(v[2], v[3])};
        *reinterpret_cast<uint2*>(&Yb[ro + q2 * 8 + hi * 4]) = pr0;
        uint2 pr1 = {pack_hu(v[4], v[5]), pack_hu(v[6], v[7])};
        *reinterpret_cast<uint2*>(&Yb[ro + 32 + q2 * 8 + hi * 4]) = pr1;
      }
    }
    // ---- S-tile B
    {
      float mm = mB;
      #pragma unroll
      for (int p = 0; p < 3; ++p) mm = fmaxf(mm, Ml[p][1][lane]);
      const float aw = fast_exp2(mB - mm);
      float ap[3];
      float ll = lB * aw;
      #pragma unroll
      for (int p = 0; p < 3; ++p) {
        ap[p] = fast_exp2(Ml[p][1][lane] - mm);
        ll += Ll[p][1][lane] * ap[p];
      }
      const float inv = 1.f / ll;
      const size_t ro = ((size_t)bb * T_ + qgB) * C_ + hh * D_;
      #pragma unroll
      for (int q2 = 0; q2 < 4; ++q2) {
        float v[8];
        #pragma unroll
        for (int e = 0; e < 4; ++e) {
          const int pr = q2 * 2 + (e >> 1), hb2 = e & 1;
          float t0 = yB0[q2 * 4 + e] * aw;
          float t1 = yB1[q2 * 4 + e] * aw;
          #pragma unroll
          for (int p = 0; p < 3; ++p) {
            t0 += bfu(Ylp[p][16 + pr][lane], hb2) * ap[p];
            t1 += bfu(Ylp[p][24 + pr][lane], hb2) * ap[p];
          }
          v[e] = t0 * inv;
          v[4 + e] = t1 * inv;
        }
        uint2 pr0 = {pack_hu(v[0], v[1]), pack_hu(v[2], v[3])};
        *reinterpret_cast<uint2*>(&Yb[ro + q2 * 8 + hi * 4]) = pr0;
        uint2 pr1 = {pack_hu(v[4], v[5]), pack_hu(v[6], v[7])};
        *reinterpret_cast<uint2*>(&Yb[ro + 32 + q2 * 8 + hi * 4]) = pr1;
      }
    }
  }
}

// ---------------------------------------------------------------- launch
extern "C" void kernel_launch(void* const* d_in, const int* in_sizes, int n_in,
                              void* d_out, int out_size, void* d_ws, size_t ws_size,
                              hipStream_t stream) {
  const float* x      = (const float*)d_in[0];
  const float* w_attn = (const float*)d_in[1];
  const float* b_attn = (const float*)d_in[2];
  const float* w_proj = (const float*)d_in[3];
  const float* b_proj = (const float*)d_in[4];
  float* out = (float*)d_out;

  char* ws = (char*)d_ws;
  size_t off = 0;
  auto alloc = [&](size_t bytes) -> void* {
    void* p = ws + off;
    off += (bytes + 255) & ~(size_t)255;
    return p;
  };
  unsigned short* xb  = (unsigned short*)alloc((size_t)M_ * K_ * 2);       // x bf16
  unsigned short* waT = (unsigned short*)alloc((size_t)N1_ * K_ * 2);      // w_attn^T bf16
  unsigned short* wpT = (unsigned short*)alloc((size_t)C_ * K_ * 2);       // w_proj^T bf16
  unsigned short* Qb  = (unsigned short*)alloc((size_t)BH_ * T_ * D_ * 2); // [BH][T][D]
  unsigned short* Kb  = (unsigned short*)alloc((size_t)BH_ * T_ * D_ * 2); // tiled
  unsigned short* Vt  = (unsigned short*)alloc((size_t)BH_ * D_ * T_ * 2); // tiled
  unsigned short* Yb  = (unsigned short*)alloc((size_t)M_ * C_ * 2);       // attn out bf16

  prep_kernel<<<3328, 256, 0, stream>>>(x, xb, w_attn, waT, w_proj, wpT);

  gemm_kernel<0><<<dim3(M_ / 128, N1_ / 128), 256, 0, stream>>>(
      xb, waT, b_attn, Qb, Kb, Vt, nullptr);

  attn_kernel<<<(T_ / 64) * BH_, 256, 0, stream>>>(Qb, Kb, Vt, Yb);

  gemm_kernel<1><<<dim3(M_ / 128, C_ / 128), 256, 0, stream>>>(
      Yb, wpT, b_proj, nullptr, nullptr, nullptr, out);
}

// Round 24
// 148.872 us; speedup vs baseline: 1.0115x; 1.0115x over previous
//
#include <hip/hip_runtime.h>
#include <stdint.h>

// Problem constants
#define B_   2
#define T_   4096
#define C_   768
#define H_   12
#define D_   64
#define BH_  24      // B_*H_
#define M_   8192    // B_*T_
#define K_   768
#define N1_  2304    // 3*C_

#define NEG_BIG (-1.0e30f)
// Q pre-scale: (1/sqrt(D)) * log2(e) -> attention runs in exp2 domain
#define QSCALE 0.18033688011112042f

typedef short bf16x8 __attribute__((ext_vector_type(8)));
typedef float f32x4  __attribute__((ext_vector_type(4)));
typedef float f32x16 __attribute__((ext_vector_type(16)));
typedef uint32_t u32x4 __attribute__((ext_vector_type(4)));
typedef int i32x2 __attribute__((ext_vector_type(2)));

typedef const __attribute__((address_space(1))) void* as1cv;
typedef __attribute__((address_space(3))) void*       as3v;

__device__ __forceinline__ void gload_lds16(const void* g, void* l) {
  __builtin_amdgcn_global_load_lds((as1cv)g, (as3v)l, 16, 0, 0);
}

// fp32 -> bf16 bits, round-to-nearest-even (input-fidelity paths).
// NOTE: v_cvt_pk_bf16_f32 inline-asm is POISONED on this toolchain (R2: NaN,
// R6: absmax 7.4e30). Software paths only.
// NOTE2 (R19): fixed-shift softmax (max-free) causes scratch spill at 128
// VGPR — keep defer-max; it also fences the scheduler's overlap window.
// NOTE3 (R20): s_setprio around attn MFMAs = -5% (no wave role-split here).
// NOTE4 (R23): XCD A-panel clustering = null/neg (working set is L3-resident;
// XCD locality engineering only pays when HBM-bound). Default mapping kept.
__device__ __forceinline__ unsigned short f2bf(float f) {
  uint32_t x = __builtin_bit_cast(uint32_t, f);
  uint32_t r = (x + 0x7fffu + ((x >> 16) & 1u)) >> 16;
  return (unsigned short)r;
}

// cheap scalar pack: round-half-up, 2 VALU ops (<=0.5 ulp; 4x absmax headroom)
__device__ __forceinline__ unsigned short f2bf_hu(float f) {
  return (unsigned short)((__builtin_bit_cast(uint32_t, f) + 0x8000u) >> 16);
}

// cheap pair pack: round-half-up + byte-select (3 VALU via v_perm_b32)
#if __has_builtin(__builtin_amdgcn_perm)
__device__ __forceinline__ uint32_t pack_hu(float lo, float hi) {
  uint32_t a = __builtin_bit_cast(uint32_t, lo) + 0x8000u;
  uint32_t b = __builtin_bit_cast(uint32_t, hi) + 0x8000u;
  return __builtin_amdgcn_perm(b, a, 0x07060302u);
}
#else
__device__ __forceinline__ uint32_t pack_hu(float lo, float hi) {
  uint32_t a = __builtin_bit_cast(uint32_t, lo) + 0x8000u;
  uint32_t b = __builtin_bit_cast(uint32_t, hi) + 0x8000u;
  return (b & 0xFFFF0000u) | (a >> 16);
}
#endif

// unpack one bf16 half of a packed pair to f32 (1-2 VALU)
__device__ __forceinline__ float bfu(uint32_t w, int hb) {
  return __builtin_bit_cast(float, hb ? (w & 0xFFFF0000u) : (w << 16));
}

// 3-input max -> v_max3_f32 (clang fuses nested fmaxf)
__device__ __forceinline__ float max3f(float a, float b, float c) {
  return fmaxf(fmaxf(a, b), c);
}

#if __has_builtin(__builtin_amdgcn_permlane32_swap)
#define HAVE_PLSWAP 1
#else
#define HAVE_PLSWAP 0
#endif

// native 2^x (v_exp_f32)
#if __has_builtin(__builtin_amdgcn_exp2f)
__device__ __forceinline__ float fast_exp2(float x) { return __builtin_amdgcn_exp2f(x); }
#else
__device__ __forceinline__ float fast_exp2(float x) { return __expf(x * 0.69314718056f); }
#endif

// ------------------- fused prep: weight transposes + x cast, ONE launch
// blocks [0, 2304): transpose+cast  a[768][2304]->oa[2304][768],
//                   b[768][768]->ob[768][768]   (32x32 tiles, 256 thr)
// blocks [2304, 3328): grid-stride cast x fp32 -> bf16 (float4 granules)
__global__ void prep_kernel(const float* __restrict__ x, unsigned short* __restrict__ xb,
                            const float* __restrict__ a, unsigned short* __restrict__ oa,
                            const float* __restrict__ b, unsigned short* __restrict__ ob) {
  __shared__ float tile[32][33];
  const int bid = blockIdx.x;
  if (bid < 2304) {
    const int bx = bid % 96, by = bid / 96;
    const float* in; unsigned short* out; int N, cb;
    if (bx < 72) { in = a; out = oa; N = 2304; cb = bx; }
    else         { in = b; out = ob; N = 768;  cb = bx - 72; }
    const int tx = threadIdx.x & 31, ty = threadIdx.x >> 5;  // 32 x 8
    const int n = cb * 32 + tx;
    #pragma unroll
    for (int r = 0; r < 4; ++r) {
      int k = by * 32 + ty + r * 8;
      tile[ty + r * 8][tx] = in[(size_t)k * N + n];
    }
    __syncthreads();
    const int k = by * 32 + tx;
    #pragma unroll
    for (int r = 0; r < 4; ++r) {
      int nn = cb * 32 + ty + r * 8;
      out[(size_t)nn * K_ + k] = f2bf(tile[tx][ty + r * 8]);
    }
  } else {
    const int n4 = M_ * K_ / 4;
    const int idx = (bid - 2304) * 256 + threadIdx.x;
    const int stride = 1024 * 256;
    for (int i = idx; i < n4; i += stride) {
      float4 v = reinterpret_cast<const float4*>(x)[i];
      ushort4 o;
      o.x = f2bf(v.x); o.y = f2bf(v.y); o.z = f2bf(v.z); o.w = f2bf(v.w);
      reinterpret_cast<ushort4*>(xb)[i] = o;
    }
  }
}

// ---------------------------------------------------------------- GEMM
// C[M][N] = A[M][768] * BT[N][768]^T + bias.  BK=64, 32 MFMAs per barrier.
// MODE-0 epilogue via LDS bounce (R18): deposit bf16 at tiled-layout
// positions in LDS, flush as 2048 coalesced 16B stores.
// MODE 1: plain fp32 store to fo[M][768] (already 64B-coalesced).
template <int MODE>
__global__ __launch_bounds__(256) void gemm_kernel(
    const unsigned short* __restrict__ A, const unsigned short* __restrict__ BT,
    const float* __restrict__ bias,
    unsigned short* __restrict__ o0, unsigned short* __restrict__ o1,
    unsigned short* __restrict__ o2, float* __restrict__ fo) {
  // A panels: [0, 8192) ushorts (two k-sub panels), B panels: [8192, 16384)
  __shared__ __align__(16) unsigned short SB[16384];
  const int tid = threadIdx.x;
  const int w = tid >> 6, lane = tid & 63;
  const int g = lane >> 4, c16 = lane & 15;
  const int wr = w >> 1, wc = w & 1;
  const int m0 = blockIdx.x * 128, n0 = blockIdx.y * 128;

  f32x4 acc[4][4] = {};

  for (int k0 = 0; k0 < K_; k0 += 64) {
    __syncthreads();
    #pragma unroll
    for (int s = 0; s < 2; ++s)
      #pragma unroll
      for (int q = 0; q < 2; ++q) {
        const int ch = (w * 2 + q) * 64 + lane;     // 0..511
        const int row = ch >> 2, kb = ch & 3;       // 128 rows x 4 x 16B
        gload_lds16(A  + (size_t)(m0 + row) * K_ + k0 + s * 32 + kb * 8,
                    &SB[s * 4096 + (w * 2 + q) * 512]);
        gload_lds16(BT + (size_t)(n0 + row) * K_ + k0 + s * 32 + kb * 8,
                    &SB[8192 + s * 4096 + (w * 2 + q) * 512]);
      }
    __syncthreads();
    #pragma unroll
    for (int s = 0; s < 2; ++s) {
      bf16x8 af[4], bfr[4];
      #pragma unroll
      for (int i = 0; i < 4; ++i) {
        af[i]  = *reinterpret_cast<const bf16x8*>(&SB[s * 4096 + (wr * 64 + i * 16 + c16) * 32 + g * 8]);
        bfr[i] = *reinterpret_cast<const bf16x8*>(&SB[8192 + s * 4096 + (wc * 64 + i * 16 + c16) * 32 + g * 8]);
      }
      #pragma unroll
      for (int i = 0; i < 4; ++i)
        #pragma unroll
        for (int j = 0; j < 4; ++j)
          acc[i][j] = __builtin_amdgcn_mfma_f32_16x16x32_bf16(af[i], bfr[j], acc[i][j], 0, 0, 0);
    }
  }

  if constexpr (MODE == 0) {
    const int which = n0 / 768;
    __syncthreads();  // staging reads complete; SB now epilogue buffer
    #pragma unroll
    for (int i = 0; i < 4; ++i) {
      const int ttl0 = wr * 64 + i * 16 + g * 4;   // local token row (j adds 0..3)
      #pragma unroll
      for (int j2 = 0; j2 < 4; ++j2) {
        const int nn = wc * 64 + j2 * 16 + c16;    // 0..127
        const float bv = bias[n0 + nn];
        const int dd = nn & 63;
        unsigned short* Lh = &SB[(nn >> 6) * 8192];
        if (which == 0) {
          const int base = ttl0 * 64 + dd;         // [ttl][dd], stride 64 per j
          #pragma unroll
          for (int j = 0; j < 4; ++j)
            Lh[base + j * 64] = f2bf_hu((acc[i][j2][j] + bv) * QSCALE);
        } else if (which == 1) {
          // K tiled: stride 8 per j (ttl&31 never crosses 32 within j-run)
          const int base = ((ttl0 >> 5) * 4 + (dd >> 4)) * 512 +
                           ((ttl0 & 31) + ((dd >> 3) & 1) * 32) * 8 + (dd & 7);
          #pragma unroll
          for (int j = 0; j < 4; ++j)
            Lh[base + j * 8] = f2bf_hu(acc[i][j2][j] + bv);
        } else {
          // V^T tiled: stride 1 per j (ttl&7 in {0,4}, no 8-crossing) -> 8B write
          const int base = (ttl0 >> 6) * 4096 + (dd >> 5) * 2048 +
                           ((ttl0 >> 4) & 3) * 512 +
                           ((dd & 31) + ((ttl0 >> 3) & 1) * 32) * 8 + (ttl0 & 7);
          uint2 pr = {pack_hu(acc[i][j2][0] + bv, acc[i][j2][1] + bv),
                      pack_hu(acc[i][j2][2] + bv, acc[i][j2][3] + bv)};
          *reinterpret_cast<uint2*>(&Lh[base]) = pr;
        }
      }
    }
    __syncthreads();
    // coalesced flush: 8 x 16B per thread
    const int tt0 = m0 & 4095, bb2 = m0 >> 12;
    const int hhA = (n0 - which * 768) >> 6;
    unsigned short* outp = (which == 0) ? o0 : (which == 1) ? o1 : o2;
    size_t gbase[2];
    #pragma unroll
    for (int h2 = 0; h2 < 2; ++h2) {
      const size_t hb = ((size_t)bb2 * H_ + hhA + h2) * T_ * D_;
      gbase[h2] = hb + (which == 0 ? (size_t)tt0 * 64
                       : which == 1 ? (size_t)(tt0 >> 5) * 2048
                                    : (size_t)(tt0 >> 6) * 4096);
    }
    #pragma unroll
    for (int c = 0; c < 8; ++c) {
      const int idx = (c * 256 + tid) * 8;     // ushort index, 16B-aligned
      const int h2 = idx >> 13, off = idx & 8191;
      u32x4 val = *reinterpret_cast<const u32x4*>(&SB[idx]);
      *reinterpret_cast<u32x4*>(&outp[gbase[h2] + off]) = val;
    }
  } else {
    #pragma unroll
    for (int i = 0; i < 4; ++i) {
      const int mbase = m0 + wr * 64 + i * 16 + g * 4;
      #pragma unroll
      for (int j2 = 0; j2 < 4; ++j2) {
        const int n = n0 + wc * 64 + j2 * 16 + c16;
        const float bv = bias[n];
        #pragma unroll
        for (int j = 0; j < 4; ++j)
          fo[(size_t)(mbase + j) * 768 + n] = acc[i][j2][j] + bv;
      }
    }
  }
}

// ---------------------------------------------------------------- flash attention
// R18 defer-max form (best measured: 79.7 us attn).
// 1 strip/block longest-first; 4 waves; 64 q-rows/wave (S-tiles A,B);
// kv round-robin (it ≡ wv mod 4); K-prefetch rotation; v_max3 reduce;
// exp2 domain; defer-max (also fences scheduler overlap — R19 spill lesson).
// No setprio (R20: -5%, no wave role-split here).
__global__ __launch_bounds__(256, 2) void attn_kernel(
    const unsigned short* __restrict__ Qb, const unsigned short* __restrict__ Kb,
    const unsigned short* __restrict__ Vt, unsigned short* __restrict__ Yb) {
  __shared__ float Ml[3][2][64];
  __shared__ float Ll[3][2][64];
  __shared__ uint32_t Ylp[3][32][64];  // [partial][reg-pair][lane], bf16x2

  const int tidx = threadIdx.x;
  const int wv = tidx >> 6;       // 0..3: kv-split partner index
  const int lane = tidx & 63;
  const int q31 = lane & 31, hi = lane >> 5;
  const int bid = blockIdx.x;
  const int bh = bid % BH_;                     // bid%8 == bh%8 -> bh->XCD locality
  const int strip = (T_ / 64 - 1) - bid / BH_;  // 63..0, longest first
  const int q0 = strip * 64;
  const int qgA = q0 + q31;        // lane's q row, S-tile A
  const int qgB = q0 + 32 + q31;   // lane's q row, S-tile B

  const int bb = bh / H_, hh = bh % H_;
  const size_t hoff = (size_t)bh * T_ * D_;
  const unsigned short* Qh = Qb + hoff;
  const unsigned short* Kh = Kb + hoff + lane * 8;  // tiled: all frag loads + lane*8
  const unsigned short* Vh = Vt + hoff + lane * 8;

  // Q fragments for both S-tiles: B-operand, col = q31, k = s*16 + hi*8 + e
  bf16x8 qfA[4], qfB[4];
  #pragma unroll
  for (int s = 0; s < 4; ++s) {
    qfA[s] = *reinterpret_cast<const bf16x8*>(&Qh[(size_t)qgA * D_ + s * 16 + hi * 8]);
    qfB[s] = *reinterpret_cast<const bf16x8*>(&Qh[(size_t)qgB * D_ + s * 16 + hi * 8]);
  }

  float mA = NEG_BIG, lA = 0.f, mB = NEG_BIG, lB = 0.f;
  f32x16 yA0 = {}, yA1 = {}, yB0 = {}, yB1 = {};

  const int nt = strip + 1;  // kv tiles 0..strip

  // prologue: K fragments for my first tile
  bf16x8 kf[8];
  {
    const unsigned short* kT = Kh + wv * 4096;
    #pragma unroll
    for (int s = 0; s < 8; ++s)
      kf[s] = *reinterpret_cast<const bf16x8*>(kT + (s >> 2) * 2048 + (s & 3) * 512);
  }

  for (int it = wv; it < nt; it += 4) {
    const int kv0 = it << 6;

    // ---- V fragments (consumed after softmax; latency hidden under QK)
    const unsigned short* vT = Vh + it * 4096;
    bf16x8 vlo[4], vhi[4];
    #pragma unroll
    for (int ks = 0; ks < 4; ++ks) {
      vlo[ks] = *reinterpret_cast<const bf16x8*>(vT + ks * 512);
      vhi[ks] = *reinterpret_cast<const bf16x8*>(vT + 2048 + ks * 512);
    }

    // ---- S^T = K * Q^T for both S-tiles (kf resident from prefetch)
    f32x16 sA0 = {}, sA1 = {}, sB0 = {}, sB1 = {};
    #pragma unroll
    for (int s = 0; s < 4; ++s) {
      sA0 = __builtin_amdgcn_mfma_f32_32x32x16_bf16(kf[s], qfA[s], sA0, 0, 0, 0);
      sB0 = __builtin_amdgcn_mfma_f32_32x32x16_bf16(kf[s], qfB[s], sB0, 0, 0, 0);
    }
    #pragma unroll
    for (int s = 0; s < 4; ++s) {
      sA1 = __builtin_amdgcn_mfma_f32_32x32x16_bf16(kf[4 + s], qfA[s], sA1, 0, 0, 0);
      sB1 = __builtin_amdgcn_mfma_f32_32x32x16_bf16(kf[4 + s], qfB[s], sB1, 0, 0, 0);
    }

    // ---- K prefetch for MY next tile (in-place rotate after last kf use)
    {
      const unsigned short* kT = Kh + (it + 4) * 4096;
      #pragma unroll
      for (int s = 0; s < 8; ++s)
        kf[s] = *reinterpret_cast<const bf16x8*>(kT + (s >> 2) * 2048 + (s & 3) * 512);
    }

    // ---- causal mask: only the diagonal tile (it == strip, wave-uniform).
    if (it == strip) {
      #pragma unroll
      for (int r = 0; r < 16; ++r) {
        const int kvl = (r & 3) + 8 * (r >> 2) + 4 * hi;
        sA0[r] = (kv0 + kvl > qgA)      ? NEG_BIG : sA0[r];
        sA1[r] = NEG_BIG;
        sB1[r] = (kv0 + 32 + kvl > qgB) ? NEG_BIG : sB1[r];
      }
    }

// ---- column max via v_max3 triples (exact): 32 values -> tmax
#define COLMAX(S0, S1, TM)                                                    \
    {                                                                         \
      float g0 = max3f(S0[0], S0[1], S0[2]);                                  \
      float g1 = max3f(S0[3], S0[4], S0[5]);                                  \
      float g2 = max3f(S0[6], S0[7], S0[8]);                                  \
      float g3 = max3f(S0[9], S0[10], S0[11]);                                \
      float g4 = max3f(S0[12], S0[13], S0[14]);                               \
      float g5 = max3f(S0[15], S1[0], S1[1]);                                 \
      float g6 = max3f(S1[2], S1[3], S1[4]);                                  \
      float g7 = max3f(S1[5], S1[6], S1[7]);                                  \
      float g8 = max3f(S1[8], S1[9], S1[10]);                                 \
      float g9 = max3f(S1[11], S1[12], S1[13]);                               \
      float ga = fmaxf(S1[14], S1[15]);                                       \
      float h0 = max3f(g0, g1, g2);                                           \
      float h1 = max3f(g3, g4, g5);                                           \
      float h2 = max3f(g6, g7, g8);                                           \
      float h3 = max3f(g9, ga, h0);                                           \
      TM = max3f(h1, h2, h3);                                                 \
      TM = fmaxf(TM, __shfl_xor(TM, 32));                                     \
    }

    // ======== softmax + PV, S-tile A ========
    {
      float tmax;
      COLMAX(sA0, sA1, tmax)

      if (__any(tmax > mA + 11.5f)) {
        const float mnew = fmaxf(mA, tmax);
        const float alpha = fast_exp2(mA - mnew);
        mA = mnew;
        lA *= alpha;
        #pragma unroll
        for (int r = 0; r < 16; ++r) { yA0[r] *= alpha; yA1[r] *= alpha; }
      }
      #pragma unroll
      for (int r = 0; r < 16; ++r) {
        sA0[r] = fast_exp2(sA0[r] - mA);
        sA1[r] = fast_exp2(sA1[r] - mA);
      }
      float a[16];
      #pragma unroll
      for (int r = 0; r < 8; ++r) a[r] = sA0[2 * r] + sA0[2 * r + 1];
      #pragma unroll
      for (int r = 0; r < 8; ++r) a[8 + r] = sA1[2 * r] + sA1[2 * r + 1];
      #pragma unroll
      for (int st = 8; st > 0; st >>= 1)
        #pragma unroll
        for (int r = 0; r < 16; ++r) if (r < st) a[r] = a[r] + a[r + st];
      float rsum = a[0];
      rsum += __shfl_xor(rsum, 32);
      lA += rsum;

      bf16x8 pf[4];
#if HAVE_PLSWAP
#define MK_PF(KS, SH, GA, HA)                                                 \
      {                                                                       \
        uint32_t g0 = pack_hu(SH[(GA)*4 + 0], SH[(GA)*4 + 1]);                \
        uint32_t g1 = pack_hu(SH[(GA)*4 + 2], SH[(GA)*4 + 3]);                \
        uint32_t h0 = pack_hu(SH[(HA)*4 + 0], SH[(HA)*4 + 1]);                \
        uint32_t h1 = pack_hu(SH[(HA)*4 + 2], SH[(HA)*4 + 3]);                \
        i32x2 r0 = __builtin_amdgcn_permlane32_swap((int)g0, (int)h0, false, false); \
        i32x2 r1 = __builtin_amdgcn_permlane32_swap((int)g1, (int)h1, false, false); \
        u32x4 t;                                                              \
        t[0] = (uint32_t)r0[0];                                               \
        t[1] = (uint32_t)r1[0];                                               \
        t[2] = (uint32_t)r0[1];                                               \
        t[3] = (uint32_t)r1[1];                                               \
        pf[KS] = __builtin_bit_cast(bf16x8, t);                               \
      }
#else
#define MK_PF(KS, SH, GA, HA)                                                 \
      {                                                                       \
        uint32_t g0 = pack_hu(SH[(GA)*4 + 0], SH[(GA)*4 + 1]);                \
        uint32_t g1 = pack_hu(SH[(GA)*4 + 2], SH[(GA)*4 + 3]);                \
        uint32_t h0 = pack_hu(SH[(HA)*4 + 0], SH[(HA)*4 + 1]);                \
        uint32_t h1 = pack_hu(SH[(HA)*4 + 2], SH[(HA)*4 + 3]);                \
        uint32_t sg0 = (uint32_t)__shfl_xor((int)g0, 32);                     \
        uint32_t sg1 = (uint32_t)__shfl_xor((int)g1, 32);                     \
        uint32_t sh0 = (uint32_t)__shfl_xor((int)h0, 32);                     \
        uint32_t sh1 = (uint32_t)__shfl_xor((int)h1, 32);                     \
        u32x4 t;                                                              \
        t[0] = hi ? sh0 : g0;                                                 \
        t[1] = hi ? sh1 : g1;                                                 \
        t[2] = hi ? h0 : sg0;                                                 \
        t[3] = hi ? h1 : sg1;                                                 \
        pf[KS] = __builtin_bit_cast(bf16x8, t);                               \
      }
#endif
      MK_PF(0, sA0, 0, 1)
      MK_PF(1, sA0, 2, 3)
      MK_PF(2, sA1, 0, 1)
      MK_PF(3, sA1, 2, 3)

      #pragma unroll
      for (int ks = 0; ks < 4; ++ks)
        yA0 = __builtin_amdgcn_mfma_f32_32x32x16_bf16(vlo[ks], pf[ks], yA0, 0, 0, 0);
      #pragma unroll
      for (int ks = 0; ks < 4; ++ks)
        yA1 = __builtin_amdgcn_mfma_f32_32x32x16_bf16(vhi[ks], pf[ks], yA1, 0, 0, 0);
    }

    // ======== softmax + PV, S-tile B ========
    {
      float tmax;
      COLMAX(sB0, sB1, tmax)

      if (__any(tmax > mB + 11.5f)) {
        const float mnew = fmaxf(mB, tmax);
        const float alpha = fast_exp2(mB - mnew);
        mB = mnew;
        lB *= alpha;
        #pragma unroll
        for (int r = 0; r < 16; ++r) { yB0[r] *= alpha; yB1[r] *= alpha; }
      }
      #pragma unroll
      for (int r = 0; r < 16; ++r) {
        sB0[r] = fast_exp2(sB0[r] - mB);
        sB1[r] = fast_exp2(sB1[r] - mB);
      }
      float a[16];
      #pragma unroll
      for (int r = 0; r < 8; ++r) a[r] = sB0[2 * r] + sB0[2 * r + 1];
      #pragma unroll
      for (int r = 0; r < 8; ++r) a[8 + r] = sB1[2 * r] + sB1[2 * r + 1];
      #pragma unroll
      for (int st = 8; st > 0; st >>= 1)
        #pragma unroll
        for (int r = 0; r < 16; ++r) if (r < st) a[r] = a[r] + a[r + st];
      float rsum = a[0];
      rsum += __shfl_xor(rsum, 32);
      lB += rsum;

      bf16x8 pf[4];
      MK_PF(0, sB0, 0, 1)
      MK_PF(1, sB0, 2, 3)
      MK_PF(2, sB1, 0, 1)
      MK_PF(3, sB1, 2, 3)
#undef MK_PF
#undef COLMAX

      #pragma unroll
      for (int ks = 0; ks < 4; ++ks)
        yB0 = __builtin_amdgcn_mfma_f32_32x32x16_bf16(vlo[ks], pf[ks], yB0, 0, 0, 0);
      #pragma unroll
      for (int ks = 0; ks < 4; ++ks)
        yB1 = __builtin_amdgcn_mfma_f32_32x32x16_bf16(vhi[ks], pf[ks], yB1, 0, 0, 0);
    }
  }

  // ---- cross-wave merge: waves 1-3 publish (bf16 pairs), wave0 combines
  if (wv > 0) {
    Ml[wv - 1][0][lane] = mA; Ml[wv - 1][1][lane] = mB;
    Ll[wv - 1][0][lane] = lA; Ll[wv - 1][1][lane] = lB;
    #pragma unroll
    for (int r = 0; r < 8; ++r) {
      Ylp[wv - 1][r][lane]      = pack_hu(yA0[2 * r], yA0[2 * r + 1]);
      Ylp[wv - 1][8 + r][lane]  = pack_hu(yA1[2 * r], yA1[2 * r + 1]);
      Ylp[wv - 1][16 + r][lane] = pack_hu(yB0[2 * r], yB0[2 * r + 1]);
      Ylp[wv - 1][24 + r][lane] = pack_hu(yB1[2 * r], yB1[2 * r + 1]);
    }
  }
  __syncthreads();
  if (wv == 0) {
    // ---- S-tile A
    {
      float mm = mA;
      #pragma unroll
      for (int p = 0; p < 3; ++p) mm = fmaxf(mm, Ml[p][0][lane]);
      const float aw = fast_exp2(mA - mm);
      float ap[3];
      float ll = lA * aw;
      #pragma unroll
      for (int p = 0; p < 3; ++p) {
        ap[p] = fast_exp2(Ml[p][0][lane] - mm);   // 0 for empty partials
        ll += Ll[p][0][lane] * ap[p];
      }
      const float inv = 1.f / ll;
      const size_t ro = ((size_t)bb * T_ + qgA) * C_ + hh * D_;
      #pragma unroll
      for (int q2 = 0; q2 < 4; ++q2) {
        float v[8];
        #pragma unroll
        for (int e = 0; e < 4; ++e) {
          const int pr = q2 * 2 + (e >> 1), hb2 = e & 1;
          float t0 = yA0[q2 * 4 + e] * aw;
          float t1 = yA1[q2 * 4 + e] * aw;
          #pragma unroll
          for (int p = 0; p < 3; ++p) {
            t0 += bfu(Ylp[p][pr][lane], hb2) * ap[p];
            t1 += bfu(Ylp[p][8 + pr][lane], hb2) * ap[p];
          }
          v[e] = t0 * inv;
          v[4 + e] = t1 * inv;
        }
        uint2 pr0 = {pack_hu(v[0], v[1]), pack_hu(v[2], v[3])};
        *reinterpret_cast<uint2*>(&Yb[ro + q2 * 8 + hi * 4]) = pr0;
        uint2 pr1 = {pack_hu(v[4], v[5]), pack_hu(v[6], v[7])};
        *reinterpret_cast<uint2*>(&Yb[ro + 32 + q2 * 8 + hi * 4]) = pr1;
      }
    }
    // ---- S-tile B
    {
      float mm = mB;
      #pragma unroll
      for (int p = 0; p < 3; ++p) mm = fmaxf(mm, Ml[p][1][lane]);
      const float aw = fast_exp2(mB - mm);
      float ap[3];
      float ll = lB * aw;
      #pragma unroll
      for (int p = 0; p < 3; ++p) {
        ap[p] = fast_exp2(Ml[p][1][lane] - mm);
        ll += Ll[p][1][lane] * ap[p];
      }
      const float inv = 1.f / ll;
      const size_t ro = ((size_t)bb * T_ + qgB) * C_ + hh * D_;
      #pragma unroll
      for (int q2 = 0; q2 < 4; ++q2) {
        float v[8];
        #pragma unroll
        for (int e = 0; e < 4; ++e) {
          const int pr = q2 * 2 + (e >> 1), hb2 = e & 1;
          float t0 = yB0[q2 * 4 + e] * aw;
          float t1 = yB1[q2 * 4 + e] * aw;
          #pragma unroll
          for (int p = 0; p < 3; ++p) {
            t0 += bfu(Ylp[p][16 + pr][lane], hb2) * ap[p];
            t1 += bfu(Ylp[p][24 + pr][lane], hb2) * ap[p];
          }
          v[e] = t0 * inv;
          v[4 + e] = t1 * inv;
        }
        uint2 pr0 = {pack_hu(v[0], v[1]), pack_hu(v[2], v[3])};
        *reinterpret_cast<uint2*>(&Yb[ro + q2 * 8 + hi * 4]) = pr0;
        uint2 pr1 = {pack_hu(v[4], v[5]), pack_hu(v[6], v[7])};
        *reinterpret_cast<uint2*>(&Yb[ro + 32 + q2 * 8 + hi * 4]) = pr1;
      }
    }
  }
}

// ---------------------------------------------------------------- launch
extern "C" void kernel_launch(void* const* d_in, const int* in_sizes, int n_in,
                              void* d_out, int out_size, void* d_ws, size_t ws_size,
                              hipStream_t stream) {
  const float* x      = (const float*)d_in[0];
  const float* w_attn = (const float*)d_in[1];
  const float* b_attn = (const float*)d_in[2];
  const float* w_proj = (const float*)d_in[3];
  const float* b_proj = (const float*)d_in[4];
  float* out = (float*)d_out;

  char* ws = (char*)d_ws;
  size_t off = 0;
  auto alloc = [&](size_t bytes) -> void* {
    void* p = ws + off;
    off += (bytes + 255) & ~(size_t)255;
    return p;
  };
  unsigned short* xb  = (unsigned short*)alloc((size_t)M_ * K_ * 2);       // x bf16
  unsigned short* waT = (unsigned short*)alloc((size_t)N1_ * K_ * 2);      // w_attn^T bf16
  unsigned short* wpT = (unsigned short*)alloc((size_t)C_ * K_ * 2);       // w_proj^T bf16
  unsigned short* Qb  = (unsigned short*)alloc((size_t)BH_ * T_ * D_ * 2); // [BH][T][D]
  unsigned short* Kb  = (unsigned short*)alloc((size_t)BH_ * T_ * D_ * 2); // tiled
  unsigned short* Vt  = (unsigned short*)alloc((size_t)BH_ * D_ * T_ * 2); // tiled
  unsigned short* Yb  = (unsigned short*)alloc((size_t)M_ * C_ * 2);       // attn out bf16

  prep_kernel<<<3328, 256, 0, stream>>>(x, xb, w_attn, waT, w_proj, wpT);

  gemm_kernel<0><<<dim3(M_ / 128, N1_ / 128), 256, 0, stream>>>(
      xb, waT, b_attn, Qb, Kb, Vt, nullptr);

  attn_kernel<<<(T_ / 64) * BH_, 256, 0, stream>>>(Qb, Kb, Vt, Yb);

  gemm_kernel<1><<<dim3(M_ / 128, C_ / 128), 256, 0, stream>>>(
      Yb, wpT, b_proj, nullptr, nullptr, nullptr, out);
}